// Round 2
// baseline (4454.435 us; speedup 1.0000x reference)
//
#include <hip/hip_runtime.h>

#define CC 256
#define HH 256
#define WD 256
#define NPIX (HH * WD)
#define SHIFT 4

// ---------------------------------------------------------------------------
// K1: pointwise conv (one 256-row part of w_qkv) for ONE batch item, with
// input roll(-4,-4) folded into the gather.
// out[oc][h][w] = sum_c wmat[oc][c] * x[c][(h+4)&255][(w+4)&255]
// grid (4 otiles, 256 h), block 256. Tile: 64 oc x 256 px, K-tiles of 16.
// ---------------------------------------------------------------------------
__global__ __launch_bounds__(256) void k_pw_roll(
    const float* __restrict__ x, const float* __restrict__ wmat,
    float* __restrict__ out)
{
    __shared__ float a_s[16][64];    // [kc][o]
    __shared__ float b_s[16][260];   // [kc][px], pad 4 for write-bank spread

    const int ot = blockIdx.x, h = blockIdx.y;
    const int tid = threadIdx.x;
    const int og = tid >> 4, pg = tid & 15;          // compute mapping
    const int o_l = tid >> 2, c4 = (tid & 3) * 4;    // A loader mapping
    const int cl = tid >> 4, w16 = (tid & 15) * 16;  // B loader mapping
    const int hs = (h + SHIFT) & 255;

    const float* xbase = x + (size_t)hs * WD;

    float acc[4][16];
#pragma unroll
    for (int i = 0; i < 4; ++i)
#pragma unroll
        for (int j = 0; j < 16; ++j) acc[i][j] = 0.f;

    for (int kt = 0; kt < 16; ++kt) {
        float4 av = *(const float4*)&wmat[(ot * 64 + o_l) * CC + kt * 16 + c4];
        a_s[c4 + 0][o_l] = av.x;
        a_s[c4 + 1][o_l] = av.y;
        a_s[c4 + 2][o_l] = av.z;
        a_s[c4 + 3][o_l] = av.w;
        const float* xr = xbase + (size_t)(kt * 16 + cl) * NPIX;
#pragma unroll
        for (int j4 = 0; j4 < 4; ++j4) {
            // SHIFT=4 and 4-runs stay contiguous across the wrap (wrap lands at 0)
            int wsrc = (w16 + j4 * 4 + SHIFT) & 255;
            *(float4*)&b_s[cl][w16 + j4 * 4] = *(const float4*)&xr[wsrc];
        }
        __syncthreads();
#pragma unroll
        for (int kc = 0; kc < 16; ++kc) {
            float4 a = *(const float4*)&a_s[kc][og * 4];   // wave-broadcast
            float aa[4] = {a.x, a.y, a.z, a.w};
#pragma unroll
            for (int j = 0; j < 4; ++j) {
                // px = pg*4 + j*64: lanes read consecutive 16B chunks (2-way, free)
                float4 bq = *(const float4*)&b_s[kc][pg * 4 + j * 64];
                float bb4[4] = {bq.x, bq.y, bq.z, bq.w};
#pragma unroll
                for (int i = 0; i < 4; ++i)
#pragma unroll
                    for (int t = 0; t < 4; ++t)
                        acc[i][j * 4 + t] += aa[i] * bb4[t];
            }
        }
        __syncthreads();
    }
#pragma unroll
    for (int i = 0; i < 4; ++i) {
        float* orow = out + ((size_t)(ot * 64 + og * 4 + i) * HH + h) * WD;
#pragma unroll
        for (int j = 0; j < 4; ++j) {
            float4 v;
            v.x = acc[i][j * 4 + 0];
            v.y = acc[i][j * 4 + 1];
            v.z = acc[i][j * 4 + 2];
            v.w = acc[i][j * 4 + 3];
            *(float4*)&orow[pg * 4 + j * 64] = v;
        }
    }
}

// ---------------------------------------------------------------------------
// K2: depthwise 3x3, zero pad, one batch item / one part.
// in: tmp[256][H][W]; out: buf2_b + part*256*NPIX.
// grid (64 hquads, 256 ch), block 256 (4 rows x 64 col-quads).
// ---------------------------------------------------------------------------
__global__ __launch_bounds__(256) void k_dw(
    const float* __restrict__ in, const float* __restrict__ wd,
    float* __restrict__ out)
{
    const int hq = blockIdx.x, ch = blockIdx.y;
    const int tid = threadIdx.x;
    const int hh = tid >> 6;
    const int w4 = (tid & 63) * 4;
    const int h = hq * 4 + hh;
    const float* ip = in + (size_t)ch * NPIX;
    const float* w9 = wd + ch * 9;
    float wv[9];
#pragma unroll
    for (int k = 0; k < 9; ++k) wv[k] = w9[k];
    float r0 = 0.f, r1 = 0.f, r2 = 0.f, r3 = 0.f;
#pragma unroll
    for (int dy = 0; dy < 3; ++dy) {
        int hy = h + dy - 1;
        if (hy < 0 || hy >= HH) continue;   // zero row pad
        const float* row = ip + (size_t)hy * WD;
        float4 cm = *(const float4*)&row[w4];
        float left = (w4 > 0) ? row[w4 - 1] : 0.f;
        float right = (w4 < 252) ? row[w4 + 4] : 0.f;
        float wa = wv[dy * 3 + 0], wb = wv[dy * 3 + 1], wc = wv[dy * 3 + 2];
        r0 += wa * left + wb * cm.x + wc * cm.y;
        r1 += wa * cm.x + wb * cm.y + wc * cm.z;
        r2 += wa * cm.y + wb * cm.z + wc * cm.w;
        r3 += wa * cm.z + wb * cm.w + wc * right;
    }
    float* op = out + (size_t)ch * NPIX + (size_t)h * WD;
    float4 res;
    res.x = r0; res.y = r1; res.z = r2; res.w = r3;
    *(float4*)&op[w4] = res;
}

// ---------------------------------------------------------------------------
// K2.5: per-pixel q squared-norm for one batch item (coalesced pass).
// qn[pix] = sum_c q[c][pix]^2   (q = first 256 channels of qkv_b)
// ---------------------------------------------------------------------------
__global__ __launch_bounds__(256) void k_qnorm(
    const float* __restrict__ qkv, float* __restrict__ qn)
{
    const int h = blockIdx.x;
    const int w = threadIdx.x;
    const float* p = qkv + (size_t)h * WD + w;
    float s = 0.f;
#pragma unroll 8
    for (int c = 0; c < 256; ++c) {
        float v = p[(size_t)c * NPIX];
        s += v * v;
    }
    qn[(size_t)h * WD + w] = s;
}

// ---------------------------------------------------------------------------
// K3: windowed channel attention, one batch item. One workgroup per 8x8 window.
// attn[c][d] = relu(temp * sum_p qhat[p][c]*khat[p][d]); out[p][d] = sum_c v[p][c]*attn[c][d]
// Per-pixel scale (1/max(||q||,eps))*(1/max(||k||,eps))*temp folded into k rows.
// LDS: k,v windows [256ch][68] (stride 68: 16B-aligned float4 rows),
// q streamed in 16-ch tiles, attn tile 16x256 through LDS.
// Output written windowed: ow[widx][p][c] so K4 gets contiguous channel reads.
// ---------------------------------------------------------------------------
__global__ __launch_bounds__(256) void k_attn(
    const float* __restrict__ qkv, const float* __restrict__ qn_buf,
    const float* __restrict__ temp_p, float* __restrict__ ow)
{
    __shared__ float k_s[256][68];
    __shared__ float v_s[256][68];
    __shared__ float q_t[16][68];
    __shared__ float at[16][257];
    __shared__ float sf[64];

    const int widx = blockIdx.x;
    const int wh = widx >> 5, wwi = widx & 31;
    const int tid = threadIdx.x;
    const int row0 = wh * 8, col0 = wwi * 8;

    const float* qbase = qkv + (size_t)row0 * WD + col0;
    const float* kbase = qbase + (size_t)256 * NPIX;
    const float* vbase = qbase + (size_t)512 * NPIX;

    // ---- load K and V windows into LDS (8-float rows per (c,dh)) ----
#pragma unroll
    for (int it = 0; it < 8; ++it) {
        int pi = it * 256 + tid;
        int c = pi >> 3, dh = pi & 7;
        const float* ks = kbase + (size_t)c * NPIX + (size_t)dh * WD;
        *(float4*)&k_s[c][dh * 8 + 0] = *(const float4*)&ks[0];
        *(float4*)&k_s[c][dh * 8 + 4] = *(const float4*)&ks[4];
        const float* vs = vbase + (size_t)c * NPIX + (size_t)dh * WD;
        *(float4*)&v_s[c][dh * 8 + 0] = *(const float4*)&vs[0];
        *(float4*)&v_s[c][dh * 8 + 4] = *(const float4*)&vs[4];
    }
    __syncthreads();

    // ---- k norms: 4 partials per pixel, reduce via at-scratch ----
    {
        int p = tid & 63, cq = tid >> 6;
        float s = 0.f;
#pragma unroll 8
        for (int i = 0; i < 64; ++i) {
            float v = k_s[cq * 64 + i][p];
            s += v * v;
        }
        ((float*)at)[tid] = s;
    }
    __syncthreads();
    if (tid < 64) {
        const float* red = (const float*)at;
        float kq = red[tid] + red[64 + tid] + red[128 + tid] + red[192 + tid];
        int dh = tid >> 3, dw = tid & 7;
        float qq = qn_buf[(size_t)(row0 + dh) * WD + col0 + dw];
        float inq = 1.f / fmaxf(sqrtf(qq), 1e-12f);
        float ink = 1.f / fmaxf(sqrtf(kq), 1e-12f);
        sf[tid] = inq * ink * temp_p[0];
    }
    __syncthreads();
    // scale k rows by sf[p]
#pragma unroll
    for (int pq = 0; pq < 16; ++pq) {
        float4 kv = *(const float4*)&k_s[tid][pq * 4];
        kv.x *= sf[pq * 4 + 0];
        kv.y *= sf[pq * 4 + 1];
        kv.z *= sf[pq * 4 + 2];
        kv.w *= sf[pq * 4 + 3];
        *(float4*)&k_s[tid][pq * 4] = kv;
    }
    __syncthreads();

    const int cg = tid >> 6, dg = tid & 63;   // attn-phase: 4c x {dg,+64,+128,+192}
    const int ph = tid >> 7, dd = tid & 127;  // out-phase: 32p-half x {dd, dd+128}

    float oa0[32], oa1[32];
#pragma unroll
    for (int i = 0; i < 32; ++i) { oa0[i] = 0.f; oa1[i] = 0.f; }

    for (int ct = 0; ct < 16; ++ct) {
        // stage raw q tile [16c][64p]
#pragma unroll
        for (int it = 0; it < 4; ++it) {
            int pi = it * 256 + tid;
            int c = pi >> 6, p = pi & 63;
            q_t[c][p] = qbase[(size_t)(ct * 16 + c) * NPIX + (size_t)(p >> 3) * WD + (p & 7)];
        }
        __syncthreads();

        float a4[4][4];
#pragma unroll
        for (int i = 0; i < 4; ++i)
#pragma unroll
            for (int j = 0; j < 4; ++j) a4[i][j] = 0.f;

#pragma unroll 4
        for (int pq = 0; pq < 16; ++pq) {
            float4 kv0 = *(const float4*)&k_s[dg + 0][pq * 4];
            float4 kv1 = *(const float4*)&k_s[dg + 64][pq * 4];
            float4 kv2 = *(const float4*)&k_s[dg + 128][pq * 4];
            float4 kv3 = *(const float4*)&k_s[dg + 192][pq * 4];
#pragma unroll
            for (int i = 0; i < 4; ++i) {
                float4 qv = *(const float4*)&q_t[cg * 4 + i][pq * 4];  // wave-broadcast
                a4[i][0] += qv.x * kv0.x + qv.y * kv0.y + qv.z * kv0.z + qv.w * kv0.w;
                a4[i][1] += qv.x * kv1.x + qv.y * kv1.y + qv.z * kv1.z + qv.w * kv1.w;
                a4[i][2] += qv.x * kv2.x + qv.y * kv2.y + qv.z * kv2.z + qv.w * kv2.w;
                a4[i][3] += qv.x * kv3.x + qv.y * kv3.y + qv.z * kv3.z + qv.w * kv3.w;
            }
        }
#pragma unroll
        for (int i = 0; i < 4; ++i) {
            at[cg * 4 + i][dg + 0] = fmaxf(a4[i][0], 0.f);
            at[cg * 4 + i][dg + 64] = fmaxf(a4[i][1], 0.f);
            at[cg * 4 + i][dg + 128] = fmaxf(a4[i][2], 0.f);
            at[cg * 4 + i][dg + 192] = fmaxf(a4[i][3], 0.f);
        }
        __syncthreads();

        // out accumulation: oa[p][d] += v[p][c]*attn[c][d]
#pragma unroll 4
        for (int c = 0; c < 16; ++c) {
            float a0 = at[c][dd];
            float a1 = at[c][dd + 128];
            const float* vr = &v_s[ct * 16 + c][ph * 32];
#pragma unroll
            for (int pq = 0; pq < 8; ++pq) {
                float4 vv = *(const float4*)&vr[pq * 4];  // wave-broadcast
                oa0[pq * 4 + 0] += vv.x * a0;  oa1[pq * 4 + 0] += vv.x * a1;
                oa0[pq * 4 + 1] += vv.y * a0;  oa1[pq * 4 + 1] += vv.y * a1;
                oa0[pq * 4 + 2] += vv.z * a0;  oa1[pq * 4 + 2] += vv.z * a1;
                oa0[pq * 4 + 3] += vv.w * a0;  oa1[pq * 4 + 3] += vv.w * a1;
            }
        }
        __syncthreads();
    }

    // windowed-layout store: ow[widx][p][d], lanes dd consecutive -> coalesced
    float* obase = ow + (size_t)widx * 64 * 256;
#pragma unroll
    for (int pp2 = 0; pp2 < 32; ++pp2) {
        obase[(size_t)(ph * 32 + pp2) * 256 + dd] = oa0[pp2];
        obase[(size_t)(ph * 32 + pp2) * 256 + dd + 128] = oa1[pp2];
    }
}

// ---------------------------------------------------------------------------
// K4: proj 1x1 conv, one batch item; un-window + roll(+4,+4) folded in.
// y[o][h][w] = sum_c w_proj[o][c] * ow[nw(hr,wr)][p(hr,wr)][c],
// (hr,wr) = ((h-4)&255, (w-4)&255). grid (4 otiles, 256 h), block 256.
// ---------------------------------------------------------------------------
__global__ __launch_bounds__(256) void k_pw_unwin(
    const float* __restrict__ ow, const float* __restrict__ wmat,
    float* __restrict__ y)
{
    __shared__ float a_s[16][64];
    __shared__ float b_s[16][260];

    const int ot = blockIdx.x, h = blockIdx.y;
    const int tid = threadIdx.x;
    const int og = tid >> 4, pg = tid & 15;
    const int o_l = tid >> 2, c4 = (tid & 3) * 4;
    const int hr = (h - SHIFT) & 255;
    const int wr = (tid - SHIFT) & 255;
    const int nw = (hr >> 3) * 32 + (wr >> 3);
    const int pp = (hr & 7) * 8 + (wr & 7);
    const float* src = ow + ((size_t)nw * 64 + pp) * 256;

    float acc[4][16];
#pragma unroll
    for (int i = 0; i < 4; ++i)
#pragma unroll
        for (int j = 0; j < 16; ++j) acc[i][j] = 0.f;

    for (int kt = 0; kt < 16; ++kt) {
        float4 av = *(const float4*)&wmat[(ot * 64 + o_l) * CC + kt * 16 + c4];
        a_s[c4 + 0][o_l] = av.x;
        a_s[c4 + 1][o_l] = av.y;
        a_s[c4 + 2][o_l] = av.z;
        a_s[c4 + 3][o_l] = av.w;
#pragma unroll
        for (int j4 = 0; j4 < 4; ++j4) {
            float4 bv = *(const float4*)&src[kt * 16 + j4 * 4];
            b_s[j4 * 4 + 0][tid] = bv.x;
            b_s[j4 * 4 + 1][tid] = bv.y;
            b_s[j4 * 4 + 2][tid] = bv.z;
            b_s[j4 * 4 + 3][tid] = bv.w;
        }
        __syncthreads();
#pragma unroll
        for (int kc = 0; kc < 16; ++kc) {
            float4 a = *(const float4*)&a_s[kc][og * 4];
            float aa[4] = {a.x, a.y, a.z, a.w};
#pragma unroll
            for (int j = 0; j < 4; ++j) {
                float4 bq = *(const float4*)&b_s[kc][pg * 4 + j * 64];
                float bb4[4] = {bq.x, bq.y, bq.z, bq.w};
#pragma unroll
                for (int i = 0; i < 4; ++i)
#pragma unroll
                    for (int t = 0; t < 4; ++t)
                        acc[i][j * 4 + t] += aa[i] * bb4[t];
            }
        }
        __syncthreads();
    }
#pragma unroll
    for (int i = 0; i < 4; ++i) {
        float* orow = y + ((size_t)(ot * 64 + og * 4 + i) * HH + h) * WD;
#pragma unroll
        for (int j = 0; j < 4; ++j) {
            float4 v;
            v.x = acc[i][j * 4 + 0];
            v.y = acc[i][j * 4 + 1];
            v.z = acc[i][j * 4 + 2];
            v.w = acc[i][j * 4 + 3];
            *(float4*)&orow[pg * 4 + j * 64] = v;
        }
    }
}

// ---------------------------------------------------------------------------
// Per-batch pipeline. Workspace (floats), reused across the 4 batch items:
//   buf2_b: 768*65536 = 50,331,648   (post-depthwise qkv, one batch)
//   tmp_b : 256*65536 = 16,777,216   (pre-dw scratch; reused as windowed out)
// total = 268,435,456 bytes (exactly 256 MiB) of d_ws.
// qn (65,536 floats) lives inside d_out's LAST batch region: it is written
// and fully consumed (k_qnorm -> k_attn) before the only writer of that
// region (k_pw_unwin for b=3) runs. All stream-ordered.
// ---------------------------------------------------------------------------
extern "C" void kernel_launch(void* const* d_in, const int* in_sizes, int n_in,
                              void* d_out, int out_size, void* d_ws, size_t ws_size,
                              hipStream_t stream)
{
    const float* x = (const float*)d_in[0];
    const float* w_qkv = (const float*)d_in[1];
    const float* w_dw = (const float*)d_in[2];
    const float* w_proj = (const float*)d_in[3];
    const float* temp = (const float*)d_in[4];
    float* y = (float*)d_out;

    float* buf2 = (float*)d_ws;                         // 50,331,648 floats
    float* tmp = buf2 + (size_t)768 * NPIX;             // 16,777,216 floats
    float* qn = y + (size_t)3 * CC * NPIX;              // scratch inside d_out

    for (int b = 0; b < 4; ++b) {
        const float* x_b = x + (size_t)b * CC * NPIX;
        float* y_b = y + (size_t)b * CC * NPIX;

        for (int part = 0; part < 3; ++part) {
            k_pw_roll<<<dim3(4, 256), 256, 0, stream>>>(
                x_b, w_qkv + (size_t)part * 256 * CC, tmp);
            k_dw<<<dim3(64, 256), 256, 0, stream>>>(
                tmp, w_dw + (size_t)part * 256 * 9, buf2 + (size_t)part * 256 * NPIX);
        }
        k_qnorm<<<dim3(256), 256, 0, stream>>>(buf2, qn);
        k_attn<<<dim3(1024), 256, 0, stream>>>(buf2, qn, temp, tmp);
        k_pw_unwin<<<dim3(4, 256), 256, 0, stream>>>(tmp, w_proj, y_b);
    }
}